// Round 4
// baseline (61504.333 us; speedup 1.0000x reference)
//
#include <hip/hip_runtime.h>
#include <cstdint>
#include <cstddef>

#define TLEN 512
#define HD   1024

typedef short bf16x8 __attribute__((ext_vector_type(8)));
typedef float f32x4  __attribute__((ext_vector_type(4)));

#define MFMA(a, b, c) __builtin_amdgcn_mfma_f32_16x16x32_bf16((a), (b), (c), 0, 0, 0)

static __device__ __forceinline__ unsigned short f2bf(float v) {
    unsigned u = __float_as_uint(v);
    u += 0x7fffu + ((u >> 16) & 1u);          // round-to-nearest-even
    return (unsigned short)(u >> 16);
}
static __device__ __forceinline__ float bf2f(unsigned short s) {
    return __uint_as_float((unsigned)s << 16);
}

// L2-bypassing coherent 16B h-load (two agent-scope relaxed 8B atomic loads).
static __device__ __forceinline__ bf16x8 ld_h16(const unsigned short* p) {
    union { unsigned long long u[2]; bf16x8 v; } r;
    r.u[0] = __hip_atomic_load((const unsigned long long*)p,
                               __ATOMIC_RELAXED, __HIP_MEMORY_SCOPE_AGENT);
    r.u[1] = __hip_atomic_load((const unsigned long long*)p + 1,
                               __ATOMIC_RELAXED, __HIP_MEMORY_SCOPE_AGENT);
    return r.v;
}

// Write-through store (past L2, to coherent L3).
static __device__ __forceinline__ void st_bypass_u16(unsigned short* p, unsigned short v) {
    unsigned vv = v;
    asm volatile("global_store_short %0, %1, off sc0 sc1" :: "v"(p), "v"(vv) : "memory");
}

// ws: bar region 8192 B: leaf i at uint[i*32] (i=0..15), root at uint[512],
//     gen replicas at uint[1024 + i*32] (i=0..15).
//     Then h buffers (ushort): hhi0[32K] hlo0[32K] hhi1[32K] hlo1[32K].
__global__ __launch_bounds__(512, 2)
void lstm_persist(const float* __restrict__ x,
                  const float* __restrict__ W,
                  const float* __restrict__ bias,
                  float* __restrict__ out,
                  unsigned* __restrict__ bar,
                  unsigned short* __restrict__ hbase)
{
    const int tid  = threadIdx.x;
    const int cb   = blockIdx.x;        // owns h-cols [cb*4, cb*4+4)
    const int wv   = tid >> 6;          // wave 0..7: K-slice of 128 (x) + 128 (h)
    const int lane = tid & 63;
    const int mn   = lane & 15;         // A: m (batch) / B: n (z-col)
    const int q    = lane >> 4;         // k = q*8 + j within a K-32 tile

    __shared__ f32x4 red[8][2][64];     // 16 KB partial accumulators
    __shared__ float cls[32][4];        // persistent cell state
    __shared__ unsigned lflag;          // wave1 -> wave0 publish handshake

    // ---- one-time: persistent W fragments (hi/lo bf16 split) ----
    const int zc  = (mn >> 2) * 1024 + cb * 4 + (mn & 3);
    const int kx0 = wv * 128;

    bf16x8 wxh[4], wxl[4], whh[4], whl[4];
    #pragma unroll
    for (int kk = 0; kk < 4; ++kk) {
        #pragma unroll
        for (int j = 0; j < 8; ++j) {
            const int r = kx0 + kk * 32 + q * 8 + j;
            float v = W[(size_t)r * 4096 + zc];
            unsigned short h = f2bf(v);
            wxh[kk][j] = (short)h;
            wxl[kk][j] = (short)f2bf(v - bf2f(h));
            float v2 = W[(size_t)(1024 + r) * 4096 + zc];
            unsigned short h2 = f2bf(v2);
            whh[kk][j] = (short)h2;
            whl[kk][j] = (short)f2bf(v2 - bf2f(h2));
        }
    }

    float bi = 0.f, bj = 0.f, bff = 0.f, bo = 0.f;
    if (tid < 128) {
        int b = tid >> 2, hc = tid & 3;
        int c0 = cb * 4 + hc;
        bi  = bias[c0];
        bj  = bias[1024 + c0];
        bff = bias[2048 + c0];
        bo  = bias[3072 + c0];
        cls[b][hc] = 0.f;
    }
    if (tid == 0) lflag = 0;
    __syncthreads();

    // ---- x register pipeline: two converted-fragment buffers ----
    bf16x8 xh0[2][4], xl0[2][4], xh1[2][4], xl1[2][4];

    auto xload = [&](int tt, int buf) {
        const size_t b0 = ((size_t)mn * TLEN + tt) * HD + kx0 + q * 8;
        const size_t b1 = ((size_t)(mn + 16) * TLEN + tt) * HD + kx0 + q * 8;
        #pragma unroll
        for (int kk = 0; kk < 4; ++kk) {
            f32x4 a0 = *(const f32x4*)(x + b0 + kk * 32);
            f32x4 a1 = *(const f32x4*)(x + b0 + kk * 32 + 4);
            f32x4 c0 = *(const f32x4*)(x + b1 + kk * 32);
            f32x4 c1 = *(const f32x4*)(x + b1 + kk * 32 + 4);
            #pragma unroll
            for (int j = 0; j < 4; ++j) {
                float vv; unsigned short h;
                vv = a0[j]; h = f2bf(vv); xh0[buf][kk][j]     = (short)h; xl0[buf][kk][j]     = (short)f2bf(vv - bf2f(h));
                vv = a1[j]; h = f2bf(vv); xh0[buf][kk][4 + j] = (short)h; xl0[buf][kk][4 + j] = (short)f2bf(vv - bf2f(h));
                vv = c0[j]; h = f2bf(vv); xh1[buf][kk][j]     = (short)h; xl1[buf][kk][j]     = (short)f2bf(vv - bf2f(h));
                vv = c1[j]; h = f2bf(vv); xh1[buf][kk][4 + j] = (short)h; xl1[buf][kk][4 + j] = (short)f2bf(vv - bf2f(h));
            }
        }
    };

    auto xmfma = [&](int buf, f32x4& A0, f32x4& A1) {
        #pragma unroll
        for (int kk = 0; kk < 4; ++kk) {
            A0 = MFMA(xh0[buf][kk], wxh[kk], A0);
            A0 = MFMA(xl0[buf][kk], wxh[kk], A0);
            A0 = MFMA(xh0[buf][kk], wxl[kk], A0);
            A1 = MFMA(xh1[buf][kk], wxh[kk], A1);
            A1 = MFMA(xl1[buf][kk], wxh[kk], A1);
            A1 = MFMA(xh1[buf][kk], wxl[kk], A1);
        }
    };

    auto hpart = [&](const unsigned short* Hh, const unsigned short* Hl,
                     f32x4& A0, f32x4& A1) {
        const int off0 = mn * HD + kx0 + q * 8;
        const int off1 = off0 + 16 * HD;
        bf16x8 ah0[4], al0[4], ah1[4], al1[4];
        #pragma unroll
        for (int kk = 0; kk < 4; ++kk) {
            ah0[kk] = ld_h16(Hh + off0 + kk * 32);
            al0[kk] = ld_h16(Hl + off0 + kk * 32);
            ah1[kk] = ld_h16(Hh + off1 + kk * 32);
            al1[kk] = ld_h16(Hl + off1 + kk * 32);
        }
        #pragma unroll
        for (int kk = 0; kk < 4; ++kk) {
            A0 = MFMA(ah0[kk], whh[kk], A0);
            A0 = MFMA(al0[kk], whh[kk], A0);
            A0 = MFMA(ah0[kk], whl[kk], A0);
            A1 = MFMA(ah1[kk], whh[kk], A1);
            A1 = MFMA(al1[kk], whh[kk], A1);
            A1 = MFMA(ah1[kk], whl[kk], A1);
        }
    };

    unsigned short* hhi0 = hbase;
    unsigned short* hlo0 = hbase + 32768;
    unsigned short* hhi1 = hbase + 65536;
    unsigned short* hlo1 = hbase + 98304;

    f32x4 accA0 = {0.f,0.f,0.f,0.f}, accA1 = {0.f,0.f,0.f,0.f};
    f32x4 accB0 = {0.f,0.f,0.f,0.f}, accB1 = {0.f,0.f,0.f,0.f};

    // prologue: x(0) converted+folded, x(1) converted and parked
    xload(TLEN - 1, 0);
    xmfma(0, accA0, accA1);
    xload(TLEN - 2, 1);

    for (int t = 0; t < TLEN; ++t) {
        const unsigned short* Hh = (t & 1) ? hhi1 : hhi0;
        const unsigned short* Hl = (t & 1) ? hlo1 : hlo0;
        unsigned short* Ph = (t & 1) ? hhi0 : hhi1;
        unsigned short* Pl = (t & 1) ? hlo0 : hlo1;

        f32x4& C0 = (t & 1) ? accB0 : accA0;   // holds xpart(t) already
        f32x4& C1 = (t & 1) ? accB1 : accA1;
        f32x4& N0 = (t & 1) ? accA0 : accB0;
        f32x4& N1 = (t & 1) ? accA1 : accB1;

        hpart(Hh, Hl, C0, C1);

        red[wv][0][lane] = C0;
        red[wv][1][lane] = C1;
        __syncthreads();

        if (tid < 128) {
            // merged reduce + epilogue
            const float* redf = (const float*)red;
            const int bb = tid >> 2, hc = tid & 3;
            float z[4] = {0.f, 0.f, 0.f, 0.f};
            #pragma unroll
            for (int g = 0; g < 4; ++g) {
                #pragma unroll
                for (int w = 0; w < 8; ++w) {
                    z[g] += redf[((w * 2 + (bb >> 4)) * 64 +
                                  ((bb & 15) >> 2) * 16 + g * 4 + hc) * 4 + (bb & 3)];
                }
            }
            float zi = z[0] + bi, zj = z[1] + bj, zf = z[2] + bff, zo = z[3] + bo;
            float co = cls[bb][hc];
            float ig = 1.f / (1.f + __expf(-zi));
            float fg = 1.f / (1.f + __expf(-(zf + 1.0f)));    // forget bias = 1.0
            float og = 1.f / (1.f + __expf(-zo));
            float jt = 2.f / (1.f + __expf(-2.f * zj)) - 1.f; // tanh
            float cn = fg * co + ig * jt;
            float tc = 2.f / (1.f + __expf(-2.f * cn)) - 1.f;
            float hn = og * tc;
            cls[bb][hc] = cn;
            __builtin_nontemporal_store(cn, &out[((size_t)bb * TLEN + t) * HD + cb * 4 + hc]);
            unsigned short hh = f2bf(hn);
            unsigned short hl = f2bf(hn - bf2f(hh));
            int wi = bb * HD + cb * 4 + hc;
            st_bypass_u16(Ph + wi, hh);
            st_bypass_u16(Pl + wi, hl);
            asm volatile("s_waitcnt vmcnt(0)" ::: "memory");   // drain this wave's publishes
            if (tid == 64)
                __hip_atomic_store(&lflag, (unsigned)(t + 1),
                                   __ATOMIC_RELAXED, __HIP_MEMORY_SCOPE_WORKGROUP);
            if (tid < 64) {
                while (__hip_atomic_load(&lflag, __ATOMIC_RELAXED,
                           __HIP_MEMORY_SCOPE_WORKGROUP) < (unsigned)(t + 1)) {}
                if (tid == 0 && t + 1 < TLEN) {
                    const unsigned target = (unsigned)t * 16u + 15u;
                    unsigned old = __hip_atomic_fetch_add(&bar[(cb >> 4) * 32], 1u,
                                       __ATOMIC_RELAXED, __HIP_MEMORY_SCOPE_AGENT);
                    if (old == target) {
                        unsigned r = __hip_atomic_fetch_add(&bar[512], 1u,
                                       __ATOMIC_RELAXED, __HIP_MEMORY_SCOPE_AGENT);
                        if (r == target) {
                            #pragma unroll
                            for (int i = 0; i < 16; ++i)
                                __hip_atomic_store(&bar[1024 + i * 32], (unsigned)(t + 1),
                                       __ATOMIC_RELAXED, __HIP_MEMORY_SCOPE_AGENT);
                        }
                    }
                }
            }
        }

        if (t + 1 < TLEN) {
            // shadow work: pure-register xpart(t+1) + prefetch/convert x(t+2)
            N0 = (f32x4){0.f,0.f,0.f,0.f};
            N1 = (f32x4){0.f,0.f,0.f,0.f};
            xmfma((t + 1) & 1, N0, N1);
            if (t + 2 < TLEN) xload(TLEN - 3 - t, t & 1);
            if (tid == 0) {
                while (__hip_atomic_load(&bar[1024 + (cb & 15) * 32], __ATOMIC_RELAXED,
                           __HIP_MEMORY_SCOPE_AGENT) < (unsigned)(t + 1)) {
                    __builtin_amdgcn_s_sleep(1);
                }
            }
            __syncthreads();
        }
    }
}

extern "C" void kernel_launch(void* const* d_in, const int* in_sizes, int n_in,
                              void* d_out, int out_size, void* d_ws, size_t ws_size,
                              hipStream_t stream)
{
    (void)in_sizes; (void)n_in; (void)out_size; (void)ws_size;
    const float* x    = (const float*)d_in[0];
    // d_in[1] = sl (unused by reference)
    const float* W    = (const float*)d_in[2];
    const float* bias = (const float*)d_in[3];
    float* out = (float*)d_out;

    unsigned* bar = (unsigned*)d_ws;
    unsigned short* hbase = (unsigned short*)((char*)d_ws + 8192);

    // zero barrier state (8 KB) + h double-buffers (256 KB)
    hipMemsetAsync(d_ws, 0, 8192 + 262144, stream);

    lstm_persist<<<256, 512, 0, stream>>>(x, W, bias, out, bar, hbase);
}